// Round 18
// baseline (704.345 us; speedup 1.0000x reference)
//
#include <hip/hip_runtime.h>
#include <stdint.h>

#define NNODES 100000
#define NEDGES 1600000
#define NB 98    // ceil(NNODES/1024)
#define WIN 25000
#define NSL 64
#define SLICE 25000   // NEDGES / NSL

typedef unsigned short ushort_t;
typedef __attribute__((ext_vector_type(8))) short bf16x8;
typedef __attribute__((ext_vector_type(4))) float f32x4;

__device__ __forceinline__ float b2f(ushort_t u) {
  union { float f; uint32_t i; } v; v.i = ((uint32_t)u) << 16; return v.f;
}
__device__ __forceinline__ float blo(uint32_t p) {
  union { float f; uint32_t i; } v; v.i = p << 16; return v.f;
}
__device__ __forceinline__ float bhi(uint32_t p) {
  union { float f; uint32_t i; } v; v.i = p & 0xffff0000u; return v.f;
}
__device__ __forceinline__ ushort_t f2b(float f) {
  union { float f; uint32_t i; } v; v.f = f;
  uint32_t r = (v.i + 0x7fffu + ((v.i >> 16) & 1u)) >> 16;
  return (ushort_t)r;
}
__device__ __forceinline__ uint32_t pack2(float lo, float hi) {
  return (uint32_t)f2b(lo) | ((uint32_t)f2b(hi) << 16);
}
__device__ __forceinline__ int clampn(int i) {
  return i < 0 ? 0 : (i >= NNODES ? NNODES - 1 : i);
}

// ---- dtype detection (proven) ----
__global__ void detect_k(const uint32_t* __restrict__ x, const uint32_t* __restrict__ ei,
                         int* __restrict__ flags) {
  if (blockIdx.x == 0 && threadIdx.x == 0) {
    int cf = 0, ci = 0;
    for (int i = 0; i < 256; ++i) {
      uint32_t u = x[i];
      uint32_t e = (u >> 7) & 0xFFu;
      if (e >= 100u && e <= 141u) cf++;
      if (ei[2 * i + 1] == 0u) ci++;
    }
    flags[0] = (cf >= 128) ? 1 : 0;
    flags[1] = (ci >= 128) ? 1 : 0;
  }
}

__global__ void zero_i32(int* __restrict__ p, int n) {
  int i = blockIdx.x * blockDim.x + threadIdx.x;
  if (i < n) p[i] = 0;
}

// ---- edge compaction (R17-proven) ----
__global__ void cvt_e32_k(const uint32_t* __restrict__ ei, int* __restrict__ src32,
                          int* __restrict__ dst32, const int* __restrict__ flags) {
  int e = blockIdx.x * blockDim.x + threadIdx.x;
  if (e >= NEDGES) return;
  int s, d;
  if (flags[1]) {
    s = (int)ei[2 * (size_t)e];
    d = (int)ei[2 * (size_t)NEDGES + 2 * (size_t)e];
  } else {
    s = (int)ei[e];
    d = (int)ei[(size_t)NEDGES + e];
  }
  src32[e] = clampn(s);
  dst32[e] = clampn(d);
}

// ---- atomic-free windowed histogram (R14-proven geometry) ----
__global__ __launch_bounds__(1024) void histw2_k(const int* __restrict__ dst32,
                                                 int* __restrict__ degp) {
  __shared__ int h[WIN];
  int b = blockIdx.x;
  int w = b >> 6, s = b & 63;
  for (int j = threadIdx.x; j < WIN; j += 1024) h[j] = 0;
  __syncthreads();
  int base = w * WIN;
  int e0 = s * SLICE, e1 = e0 + SLICE;
  for (int e = e0 + threadIdx.x; e < e1; e += 1024) {
    int j = dst32[e] - base;
    if ((unsigned)j < (unsigned)WIN) atomicAdd(&h[j], 1);
  }
  __syncthreads();
  int* dp = degp + (size_t)s * NNODES + base;
  for (int j = threadIdx.x; j < WIN; j += 1024) dp[j] = h[j];
}

__global__ void hreduce_k(int* __restrict__ degp, int* __restrict__ deg) {
  int n = blockIdx.x * blockDim.x + threadIdx.x;
  if (n >= NNODES) return;
  int run = 0;
  for (int s = 0; s < NSL; ++s) {
    size_t idx = (size_t)s * NNODES + n;
    int t = degp[idx];
    degp[idx] = run;
    run += t;
  }
  deg[n] = run;
}

// ---- hierarchical scan (proven) ----
__global__ __launch_bounds__(1024) void scan1_k(const int* __restrict__ deg, int* __restrict__ bsum) {
  __shared__ int wsum[16];
  int tid = threadIdx.x;
  int i = blockIdx.x * 1024 + tid;
  int v = (i < NNODES) ? deg[i] : 0;
  #pragma unroll
  for (int d = 32; d >= 1; d >>= 1) v += __shfl_down(v, d);
  if ((tid & 63) == 0) wsum[tid >> 6] = v;
  __syncthreads();
  if (tid == 0) {
    int t = 0;
    #pragma unroll
    for (int w = 0; w < 16; ++w) t += wsum[w];
    bsum[blockIdx.x] = t;
  }
}

__global__ void scan2_k(int* __restrict__ bsum, int* __restrict__ offs) {
  if (blockIdx.x == 0 && threadIdx.x == 0) {
    int run = 0;
    for (int b = 0; b < NB; ++b) { int t = bsum[b]; bsum[b] = run; run += t; }
    offs[NNODES] = run;
  }
}

__global__ __launch_bounds__(1024) void scan3_k(const int* __restrict__ deg, const int* __restrict__ bsum,
                                                int* __restrict__ offs, int* __restrict__ cursor,
                                                float* __restrict__ invd) {
  __shared__ int wsum[16];
  int tid = threadIdx.x;
  int lane = tid & 63, wid = tid >> 6;
  int i = blockIdx.x * 1024 + tid;
  int v = (i < NNODES) ? deg[i] : 0;
  int s = v;
  #pragma unroll
  for (int d = 1; d < 64; d <<= 1) {
    int t = __shfl_up(s, d);
    if (lane >= d) s += t;
  }
  if (lane == 63) wsum[wid] = s;
  __syncthreads();
  int wprefix = 0;
  #pragma unroll
  for (int w = 0; w < 16; ++w)
    if (w < wid) wprefix += wsum[w];
  if (i < NNODES) {
    int excl = bsum[blockIdx.x] + wprefix + s - v;
    offs[i] = excl;
    cursor[i] = excl;
    invd[i] = 1.0f / fmaxf((float)v, 1.0f);
  }
}

// ---- 4-pass windowed scatter (proven) ----
__global__ void scatter4_k(const int* __restrict__ src32, const int* __restrict__ dst32,
                           int* __restrict__ cursor, int* __restrict__ csr,
                           int lo, int hi) {
  int e = blockIdx.x * blockDim.x + threadIdx.x;
  if (e >= NEDGES) return;
  int d = dst32[e];
  if (d < lo || d >= hi) return;
  int p = atomicAdd(&cursor[d], 1);
  if (p >= 0 && p < NEDGES) csr[p] = src32[e];
}

// ---- cvt kernels (proven) ----
template <bool BF16>
__global__ void cvt_packx_k(const void* __restrict__ src, uint32_t* __restrict__ dst, int npairs,
                            const int* __restrict__ flags) {
  if (flags[0] != (BF16 ? 1 : 0)) return;
  int i = blockIdx.x * blockDim.x + threadIdx.x;
  if (i < npairs) {
    if constexpr (BF16) dst[i] = ((const uint32_t*)src)[i];
    else {
      const float* s = (const float*)src;
      dst[i] = pack2(s[2 * i], s[2 * i + 1]);
    }
  }
}

template <bool BF16>
__global__ void cvt_outp_k(const uint32_t* __restrict__ src, void* __restrict__ dst, int npairs,
                           const int* __restrict__ flags) {
  if (flags[0] != (BF16 ? 1 : 0)) return;
  int i = blockIdx.x * blockDim.x + threadIdx.x;
  if (i < npairs) {
    if constexpr (BF16) ((uint32_t*)dst)[i] = src[i];
    else {
      uint32_t w = src[i];
      float* d = (float*)dst;
      d[2 * i] = blo(w);
      d[2 * i + 1] = bhi(w);
    }
  }
}

template <bool BF16>
__global__ void cvt_out_k(const float* __restrict__ src, void* __restrict__ dst, int n,
                          const int* __restrict__ flags) {
  if (flags[0] != (BF16 ? 1 : 0)) return;
  int i = blockIdx.x * blockDim.x + threadIdx.x;
  if (i < n) {
    if constexpr (BF16) ((ushort_t*)dst)[i] = f2b(src[i]);
    else ((float*)dst)[i] = src[i];
  }
}

struct WPtrs { const void* p[18]; int sz[18]; int off[18]; };

template <bool BF16>
__global__ void cvt_w_k(WPtrs w, float* __restrict__ dst, const int* __restrict__ flags) {
  if (flags[0] != (BF16 ? 1 : 0)) return;
  int a = blockIdx.x;
  int sz = w.sz[a], off = w.off[a];
  for (int t = threadIdx.x; t < sz; t += blockDim.x) {
    dst[off + t] = BF16 ? b2f(((const ushort_t*)w.p[a])[t]) : ((const float*)w.p[a])[t];
  }
}

// ---- F=3 aggregation (proven) ----
template <bool ADD_U>
__global__ __launch_bounds__(256) void agg3_k(const float* __restrict__ feat, const int* __restrict__ csr,
                                              const int* __restrict__ offs, const float* __restrict__ invd,
                                              const float* __restrict__ u, float* __restrict__ out) {
  int n = blockIdx.x * blockDim.x + threadIdx.x;
  if (n >= NNODES) return;
  int k0 = offs[n], k1 = offs[n + 1];
  float a0 = 0.f, a1 = 0.f, a2 = 0.f;
  int k = k0;
  for (; k + 4 <= k1; k += 4) {
    const float* r0 = feat + (size_t)clampn(csr[k]) * 3;
    const float* r1 = feat + (size_t)clampn(csr[k + 1]) * 3;
    const float* r2 = feat + (size_t)clampn(csr[k + 2]) * 3;
    const float* r3 = feat + (size_t)clampn(csr[k + 3]) * 3;
    a0 += r0[0] + r1[0] + r2[0] + r3[0];
    a1 += r0[1] + r1[1] + r2[1] + r3[1];
    a2 += r0[2] + r1[2] + r2[2] + r3[2];
  }
  for (; k < k1; ++k) {
    const float* r = feat + (size_t)clampn(csr[k]) * 3;
    a0 += r[0]; a1 += r[1]; a2 += r[2];
  }
  float iv = invd[n];
  a0 *= iv; a1 *= iv; a2 *= iv;
  if constexpr (ADD_U) {
    a0 += u[(size_t)n * 3];
    a1 += u[(size_t)n * 3 + 1];
    a2 += u[(size_t)n * 3 + 2];
  }
  out[(size_t)n * 3]     = a0;
  out[(size_t)n * 3 + 1] = a1;
  out[(size_t)n * 3 + 2] = a2;
}

// ---- packed-bf16 aggregation v4 (R15-proven; row-major PAIRS=20 paths) ----
template <int PAIRS, bool ADD_U>
__global__ __launch_bounds__(256) void aggp4_k(const uint32_t* __restrict__ feat, const int* __restrict__ csr,
                                               const int* __restrict__ offs, const float* __restrict__ invd,
                                               const uint32_t* __restrict__ u, uint32_t* __restrict__ out) {
  constexpr int HP = PAIRS / 2;
  int lane = threadIdx.x & 63;
  int n = (blockIdx.x * blockDim.x + threadIdx.x) >> 6;
  if (n >= NNODES) return;
  int q = lane >> 4;
  int p = lane & 15;
  int k0 = offs[n], k1 = offs[n + 1];
  float a0 = 0.f, a1 = 0.f, a2 = 0.f, a3 = 0.f;
  int k = k0;
  for (; k + 8 <= k1; k += 8) {
    int r0 = clampn(csr[k + q]);
    int r1 = clampn(csr[k + 4 + q]);
    if (p < HP) {
      uint2 w0 = ((const uint2*)(feat + (size_t)r0 * PAIRS))[p];
      uint2 w1 = ((const uint2*)(feat + (size_t)r1 * PAIRS))[p];
      a0 += blo(w0.x) + blo(w1.x);
      a1 += bhi(w0.x) + bhi(w1.x);
      a2 += blo(w0.y) + blo(w1.y);
      a3 += bhi(w0.y) + bhi(w1.y);
    }
  }
  for (; k + 4 <= k1; k += 4) {
    int r0 = clampn(csr[k + q]);
    if (p < HP) {
      uint2 w0 = ((const uint2*)(feat + (size_t)r0 * PAIRS))[p];
      a0 += blo(w0.x); a1 += bhi(w0.x); a2 += blo(w0.y); a3 += bhi(w0.y);
    }
  }
  int rem = k1 - k;
  if (q < rem && p < HP) {
    int r0 = clampn(csr[k + q]);
    uint2 w0 = ((const uint2*)(feat + (size_t)r0 * PAIRS))[p];
    a0 += blo(w0.x); a1 += bhi(w0.x); a2 += blo(w0.y); a3 += bhi(w0.y);
  }
  a0 += __shfl_xor(a0, 16); a0 += __shfl_xor(a0, 32);
  a1 += __shfl_xor(a1, 16); a1 += __shfl_xor(a1, 32);
  a2 += __shfl_xor(a2, 16); a2 += __shfl_xor(a2, 32);
  a3 += __shfl_xor(a3, 16); a3 += __shfl_xor(a3, 32);
  if (q == 0 && p < HP) {
    float iv = invd[n];
    float v0 = a0 * iv, v1 = a1 * iv, v2 = a2 * iv, v3 = a3 * iv;
    if constexpr (ADD_U) {
      uint2 uw = ((const uint2*)(u + (size_t)n * PAIRS))[p];
      v0 += blo(uw.x); v1 += bhi(uw.x); v2 += blo(uw.y); v3 += bhi(uw.y);
    }
    uint2 ow;
    ow.x = pack2(v0, v1);
    ow.y = pack2(v2, v3);
    ((uint2*)(out + (size_t)n * PAIRS))[p] = ow;
  }
}

// ---- slice-major aggregation (F=64): blockIdx%8 = slice -> one XCD owns one 1.6MB slice ----
// Layout S: word w of row r lives at S[(w>>2)*N*4 + r*4 + (w&3)]. Wave: 16 neighbors x 4 words.
__global__ __launch_bounds__(256) void aggs_k(const uint32_t* __restrict__ tblS, const int* __restrict__ csr,
                                              const int* __restrict__ offs, const float* __restrict__ invd,
                                              uint32_t* __restrict__ outS) {
  int b = blockIdx.x;
  int s = b & 7;
  int wid = threadIdx.x >> 6;
  int lane = threadIdx.x & 63;
  int v = (b >> 3) * 4 + wid;                  // wave index within slice: 0..1023
  int nb = lane >> 2;                          // neighbor slot 0..15
  int w = lane & 3;                            // word within 16B slice entry
  const uint32_t* tbl = tblS + (size_t)s * NNODES * 4;
  uint32_t* out = outS + (size_t)s * NNODES * 4;
  for (int n = v; n < NNODES; n += 1024) {
    int k0 = offs[n], k1 = offs[n + 1];
    float aL = 0.f, aH = 0.f;
    int k = k0;
    for (; k + 16 <= k1; k += 16) {
      int r = clampn(csr[k + nb]);
      uint32_t x = tbl[(size_t)r * 4 + w];
      aL += blo(x); aH += bhi(x);
    }
    if (k + nb < k1) {
      int r = clampn(csr[k + nb]);
      uint32_t x = tbl[(size_t)r * 4 + w];
      aL += blo(x); aH += bhi(x);
    }
    aL += __shfl_xor(aL, 4); aL += __shfl_xor(aL, 8); aL += __shfl_xor(aL, 16); aL += __shfl_xor(aL, 32);
    aH += __shfl_xor(aH, 4); aH += __shfl_xor(aH, 8); aH += __shfl_xor(aH, 16); aH += __shfl_xor(aH, 32);
    if (lane < 4) {
      float iv = invd[n];
      out[(size_t)n * 4 + w] = pack2(aL * iv, aH * iv);
    }
  }
}

// ---- MFMA fused linear with per-operand layouts ----
// AL/BL: 0=f32 row, 1=packed row, 2=packed slice (F_IN==64 only). OUTL: 0=f32, 1=packed row, 2=packed slice (F_OUT==64).
template <int F_IN, int F_OUT, bool DUAL, bool RELU, int AL, int BL, int OUTL>
__global__ __launch_bounds__(256) void mgemm_k(const void* __restrict__ Av, const void* __restrict__ Bv,
                                               const float* __restrict__ W1, const float* __restrict__ W2,
                                               const float* __restrict__ Wb,
                                               void* __restrict__ C1v, void* __restrict__ C2v) {
  constexpr int KS = (F_IN + 31) / 32;
  constexpr int JT = (F_OUT + 15) / 16;
  constexpr int PP = F_IN / 2;
  int lane = threadIdx.x & 63;
  int wid  = threadIdx.x >> 6;
  int tile = blockIdx.x * 4 + wid;
  if (tile * 16 >= NNODES) return;
  int l15 = lane & 15, l4 = lane >> 4;

  bf16x8 w1f[KS][JT], w2f[KS][JT];
  float bv[JT];
  #pragma unroll
  for (int ks = 0; ks < KS; ++ks) {
    #pragma unroll
    for (int jt = 0; jt < JT; ++jt) {
      int col = jt * 16 + l15;
      #pragma unroll
      for (int j = 0; j < 8; ++j) {
        int k = ks * 32 + l4 * 8 + j;
        bool ok = (k < F_IN) && (col < F_OUT);
        w1f[ks][jt][j] = ok ? (short)f2b(W1[k * F_OUT + col]) : (short)0;
        w2f[ks][jt][j] = ok ? (short)f2b(W2[k * F_OUT + col]) : (short)0;
      }
    }
  }
  #pragma unroll
  for (int jt = 0; jt < JT; ++jt) {
    int col = jt * 16 + l15;
    bv[jt] = (col < F_OUT) ? Wb[col] : 0.f;
  }

  int row = tile * 16 + l15;
  bf16x8 af[KS], bfr[KS];

  auto loadfrag = [&](const void* Pv, bf16x8 (&fr)[KS], auto layout) {
    constexpr int L = decltype(layout)::value;
    if constexpr (L == 2) {
      #pragma unroll
      for (int ks = 0; ks < KS; ++ks) {
        uint4 vv = *(const uint4*)((const uint32_t*)Pv + ((size_t)(ks * 4 + l4) * NNODES + row) * 4);
        fr[ks][0] = (short)(vv.x & 0xffffu); fr[ks][1] = (short)(vv.x >> 16);
        fr[ks][2] = (short)(vv.y & 0xffffu); fr[ks][3] = (short)(vv.y >> 16);
        fr[ks][4] = (short)(vv.z & 0xffffu); fr[ks][5] = (short)(vv.z >> 16);
        fr[ks][6] = (short)(vv.w & 0xffffu); fr[ks][7] = (short)(vv.w >> 16);
      }
    } else if constexpr (L == 1) {
      const uint32_t* Prow = (const uint32_t*)Pv + (size_t)row * PP;
      #pragma unroll
      for (int ks = 0; ks < KS; ++ks) {
        #pragma unroll
        for (int w4 = 0; w4 < 4; ++w4) {
          int word = ks * 16 + l4 * 4 + w4;
          uint32_t v = (word < PP) ? Prow[word] : 0u;
          fr[ks][2 * w4]     = (short)(v & 0xffffu);
          fr[ks][2 * w4 + 1] = (short)(v >> 16);
        }
      }
    } else {
      const float* Prow = (const float*)Pv + (size_t)row * F_IN;
      #pragma unroll
      for (int ks = 0; ks < KS; ++ks) {
        #pragma unroll
        for (int j = 0; j < 8; ++j) {
          int k = ks * 32 + l4 * 8 + j;
          fr[ks][j] = (k < F_IN) ? (short)f2b(Prow[k]) : (short)0;
        }
      }
    }
  };
  loadfrag(Av, af, std::integral_constant<int, AL>{});
  if constexpr (!DUAL) loadfrag(Bv, bfr, std::integral_constant<int, BL>{});

  f32x4 acc1[JT], acc2[DUAL ? JT : 1];
  #pragma unroll
  for (int jt = 0; jt < JT; ++jt) {
    acc1[jt] = (f32x4)(0.f);
    if constexpr (DUAL) acc2[jt] = (f32x4)(0.f);
  }

  #pragma unroll
  for (int ks = 0; ks < KS; ++ks) {
    #pragma unroll
    for (int jt = 0; jt < JT; ++jt) {
      acc1[jt] = __builtin_amdgcn_mfma_f32_16x16x32_bf16(af[ks], w1f[ks][jt], acc1[jt], 0, 0, 0);
      if constexpr (DUAL)
        acc2[jt] = __builtin_amdgcn_mfma_f32_16x16x32_bf16(af[ks], w2f[ks][jt], acc2[jt], 0, 0, 0);
      else
        acc1[jt] = __builtin_amdgcn_mfma_f32_16x16x32_bf16(bfr[ks], w2f[ks][jt], acc1[jt], 0, 0, 0);
    }
  }

  auto store1 = [&](void* Cv, float vv, int orow, int col, float pv) {
    if constexpr (OUTL == 2) {
      int wo = col >> 1;
      if (((lane & 1) == 0) && col < F_OUT)
        ((uint32_t*)Cv)[((size_t)(wo >> 2) * NNODES + orow) * 4 + (wo & 3)] = pack2(vv, pv);
    } else if constexpr (OUTL == 1) {
      if (((lane & 1) == 0) && col < F_OUT)
        ((uint32_t*)Cv)[(size_t)orow * (F_OUT / 2) + (col >> 1)] = pack2(vv, pv);
    } else {
      if (col < F_OUT)
        ((float*)Cv)[(size_t)orow * F_OUT + col] = vv;
    }
  };

  #pragma unroll
  for (int jt = 0; jt < JT; ++jt) {
    int col = jt * 16 + l15;
    #pragma unroll
    for (int r = 0; r < 4; ++r) {
      int orow = tile * 16 + l4 * 4 + r;
      if constexpr (DUAL) {
        float v1 = acc1[jt][r];
        float v2 = acc2[jt][r] + bv[jt];
        float p1 = (OUTL != 0) ? __shfl_xor(v1, 1) : 0.f;
        float p2 = (OUTL != 0) ? __shfl_xor(v2, 1) : 0.f;
        store1(C1v, v1, orow, col, p1);
        store1(C2v, v2, orow, col, p2);
      } else {
        float v = acc1[jt][r] + bv[jt];
        if constexpr (RELU) v = fmaxf(v, 0.f);
        float pv = (OUTL != 0) ? __shfl_xor(v, 1) : 0.f;
        store1(C1v, v, orow, col, pv);
      }
    }
  }
}

extern "C" void kernel_launch(void* const* d_in, const int* in_sizes, int n_in,
                              void* d_out, int out_size, void* d_ws, size_t ws_size,
                              hipStream_t stream) {
  const uint32_t* xw = (const uint32_t*)d_in[0];
  const uint32_t* ei = (const uint32_t*)d_in[1];

  char* ws = (char*)d_ws;
  size_t off = 0;
  auto carve = [&](size_t bytes) -> char* {
    char* p = ws + off;
    off = (off + bytes + 255) & ~(size_t)255;
    return p;
  };
  int* flags     = (int*)carve(8);
  int* deg       = (int*)carve((size_t)NNODES * 4);
  int* offs      = (int*)carve((size_t)(NNODES + 1) * 4);
  int* cursor    = (int*)carve((size_t)NNODES * 4);
  float* invd    = (float*)carve((size_t)NNODES * 4);
  int* bsum      = (int*)carve((size_t)NB * 4);
  int* csr       = (int*)carve((size_t)NEDGES * 4);
  float* wf      = (float*)carve((size_t)32768 * 4);
  uint32_t* xp   = (uint32_t*)carve((size_t)NNODES * 20 * 4);
  uint32_t* mp   = (uint32_t*)carve((size_t)NNODES * 20 * 4);
  uint32_t* b0p  = (uint32_t*)carve((size_t)NNODES * 32 * 4);
  uint32_t* b1p  = (uint32_t*)carve((size_t)NNODES * 32 * 4);
  uint32_t* b2p  = (uint32_t*)carve((size_t)NNODES * 32 * 4);
  uint32_t* y40p = (uint32_t*)carve((size_t)NNODES * 20 * 4);
  uint32_t* u40p = (uint32_t*)carve((size_t)NNODES * 20 * 4);
  uint32_t* xrp  = (uint32_t*)carve((size_t)NNODES * 20 * 4);
  float* y3f     = (float*)carve((size_t)NNODES * 3 * 4);
  float* u3f     = (float*)carve((size_t)NNODES * 3 * 4);
  float* zf      = (float*)carve((size_t)NNODES * 3 * 4);
  float* m3f     = (float*)carve((size_t)NNODES * 3 * 4);

  // degp overlays b0p+b1p (25.6 MB); src32/dst32 overlays b2p (12.8 MB). All first
  // written by enc1/enc2 kernels, strictly after the CSR build completes.
  int* degp = (int*)b0p;
  int* src32 = (int*)b2p;
  int* dst32 = src32 + NEDGES;

  static const int wsz[18] = {2560, 2560, 64, 4096, 4096, 64, 192, 192, 3,
                              192, 192, 64, 4096, 4096, 64, 2560, 2560, 40};
  WPtrs wp;
  int woff = 0;
  for (int i = 0; i < 18; ++i) {
    wp.p[i] = d_in[2 + i];
    wp.sz[i] = wsz[i];
    wp.off[i] = woff;
    woff += wsz[i];
  }
  const float* W[18];
  for (int i = 0; i < 18; ++i) W[i] = wf + wp.off[i];

  // ---- detect + CSR build (R17-proven) ----
  detect_k<<<1, 64, 0, stream>>>(xw, ei, flags);
  const int EB = (NEDGES + 255) / 256;
  cvt_e32_k<<<EB, 256, 0, stream>>>(ei, src32, dst32, flags);
  zero_i32<<<EB, 256, 0, stream>>>(csr, NEDGES);
  histw2_k<<<4 * NSL, 1024, 0, stream>>>(dst32, degp);
  hreduce_k<<<(NNODES + 255) / 256, 256, 0, stream>>>(degp, deg);
  scan1_k<<<NB, 1024, 0, stream>>>(deg, bsum);
  scan2_k<<<1, 64, 0, stream>>>(bsum, offs);
  scan3_k<<<NB, 1024, 0, stream>>>(deg, bsum, offs, cursor, invd);
  scatter4_k<<<EB, 256, 0, stream>>>(src32, dst32, cursor, csr, 0, 25000);
  scatter4_k<<<EB, 256, 0, stream>>>(src32, dst32, cursor, csr, 25000, 50000);
  scatter4_k<<<EB, 256, 0, stream>>>(src32, dst32, cursor, csr, 50000, 75000);
  scatter4_k<<<EB, 256, 0, stream>>>(src32, dst32, cursor, csr, 75000, 100000);

  // ---- convert x (packed) + weights (f32 arena) ----
  const int NXP = NNODES * 20;
  cvt_packx_k<false><<<(NXP + 255) / 256, 256, 0, stream>>>(d_in[0], xp, NXP, flags);
  cvt_packx_k<true ><<<(NXP + 255) / 256, 256, 0, stream>>>(d_in[0], xp, NXP, flags);
  cvt_w_k<false><<<18, 256, 0, stream>>>(wp, wf, flags);
  cvt_w_k<true ><<<18, 256, 0, stream>>>(wp, wf, flags);

  const int AGGW_BLOCKS = (NNODES * 64 + 255) / 256;
  const int AGGS_BLOCKS = 2048;   // 8 slices x 256 blocks
  const int AGG3_BLOCKS = (NNODES + 255) / 256;
  const int MG = (NNODES / 16 + 3) / 4;

  // enc1 (40 -> 64): row-major agg; mgemm writes b1p SLICE-major
  aggp4_k<20, false><<<AGGW_BLOCKS, 256, 0, stream>>>(xp, csr, offs, invd, nullptr, mp);
  mgemm_k<40, 64, false, true, 1, 1, 2><<<MG, 256, 0, stream>>>(mp, xp, W[0], W[1], W[2], b1p, nullptr);
  // enc2 (64 -> 64): slice-major agg (per-XCD L2-resident); all slice-major
  aggs_k<<<AGGS_BLOCKS, 256, 0, stream>>>(b1p, csr, offs, invd, b0p);
  mgemm_k<64, 64, false, true, 2, 2, 2><<<MG, 256, 0, stream>>>(b0p, b1p, W[3], W[4], W[5], b2p, nullptr);
  // enc3 (64 -> 3): transform-first; A slice-major, f32 outs
  mgemm_k<64, 3, true, false, 2, 0, 0><<<MG, 256, 0, stream>>>(b2p, nullptr, W[6], W[7], W[8], y3f, u3f);
  agg3_k<true><<<AGG3_BLOCKS, 256, 0, stream>>>(y3f, csr, offs, invd, u3f, zf);
  // dec1 (3 -> 64): f32 in; mgemm writes b1p SLICE-major
  agg3_k<false><<<AGG3_BLOCKS, 256, 0, stream>>>(zf, csr, offs, invd, nullptr, m3f);
  mgemm_k<3, 64, false, true, 0, 0, 2><<<MG, 256, 0, stream>>>(m3f, zf, W[9], W[10], W[11], b1p, nullptr);
  // dec2 (64 -> 64): slice-major agg
  aggs_k<<<AGGS_BLOCKS, 256, 0, stream>>>(b1p, csr, offs, invd, b0p);
  mgemm_k<64, 64, false, true, 2, 2, 2><<<MG, 256, 0, stream>>>(b0p, b1p, W[12], W[13], W[14], b2p, nullptr);
  // dec3 (64 -> 40): transform-first; A slice-major, row-packed outs
  mgemm_k<64, 40, true, false, 2, 0, 1><<<MG, 256, 0, stream>>>(b2p, nullptr, W[15], W[16], W[17], y40p, u40p);
  aggp4_k<20, true><<<AGGW_BLOCKS, 256, 0, stream>>>(y40p, csr, offs, invd, u40p, xrp);

  // ---- outputs (proven) ----
  const int NX = NNODES * 40;
  const int NZ = NNODES * 3;
  cvt_outp_k<false><<<(NXP + 255) / 256, 256, 0, stream>>>(xrp, d_out, NXP, flags);
  cvt_outp_k<true ><<<(NXP + 255) / 256, 256, 0, stream>>>(xrp, d_out, NXP, flags);
  cvt_out_k<false><<<(NZ + 255) / 256, 256, 0, stream>>>(zf, (float*)d_out + NX, NZ, flags);
  cvt_out_k<true ><<<(NZ + 255) / 256, 256, 0, stream>>>(zf, (ushort_t*)d_out + NX, NZ, flags);
  (void)in_sizes; (void)n_in; (void)out_size; (void)ws_size;
}

// Round 19
// 487.713 us; speedup vs baseline: 1.4442x; 1.4442x over previous
//
#include <hip/hip_runtime.h>
#include <stdint.h>

#define NNODES 100000
#define NEDGES 1600000
#define NB 98    // ceil(NNODES/1024)
#define WIN 25000
#define NSL 64
#define SLICE 25000   // NEDGES / NSL

typedef unsigned short ushort_t;
typedef __attribute__((ext_vector_type(8))) short bf16x8;
typedef __attribute__((ext_vector_type(4))) float f32x4;

__device__ __forceinline__ float b2f(ushort_t u) {
  union { float f; uint32_t i; } v; v.i = ((uint32_t)u) << 16; return v.f;
}
__device__ __forceinline__ float blo(uint32_t p) {
  union { float f; uint32_t i; } v; v.i = p << 16; return v.f;
}
__device__ __forceinline__ float bhi(uint32_t p) {
  union { float f; uint32_t i; } v; v.i = p & 0xffff0000u; return v.f;
}
__device__ __forceinline__ ushort_t f2b(float f) {
  union { float f; uint32_t i; } v; v.f = f;
  uint32_t r = (v.i + 0x7fffu + ((v.i >> 16) & 1u)) >> 16;
  return (ushort_t)r;
}
__device__ __forceinline__ uint32_t pack2(float lo, float hi) {
  return (uint32_t)f2b(lo) | ((uint32_t)f2b(hi) << 16);
}
__device__ __forceinline__ int clampn(int i) {
  return i < 0 ? 0 : (i >= NNODES ? NNODES - 1 : i);
}

// ---- dtype detection (proven) ----
__global__ void detect_k(const uint32_t* __restrict__ x, const uint32_t* __restrict__ ei,
                         int* __restrict__ flags) {
  if (blockIdx.x == 0 && threadIdx.x == 0) {
    int cf = 0, ci = 0;
    for (int i = 0; i < 256; ++i) {
      uint32_t u = x[i];
      uint32_t e = (u >> 7) & 0xFFu;
      if (e >= 100u && e <= 141u) cf++;
      if (ei[2 * i + 1] == 0u) ci++;
    }
    flags[0] = (cf >= 128) ? 1 : 0;
    flags[1] = (ci >= 128) ? 1 : 0;
  }
}

__global__ void zero_i32(int* __restrict__ p, int n) {
  int i = blockIdx.x * blockDim.x + threadIdx.x;
  if (i < n) p[i] = 0;
}

// ---- edge compaction (R17-proven) ----
__global__ void cvt_e32_k(const uint32_t* __restrict__ ei, int* __restrict__ src32,
                          int* __restrict__ dst32, const int* __restrict__ flags) {
  int e = blockIdx.x * blockDim.x + threadIdx.x;
  if (e >= NEDGES) return;
  int s, d;
  if (flags[1]) {
    s = (int)ei[2 * (size_t)e];
    d = (int)ei[2 * (size_t)NEDGES + 2 * (size_t)e];
  } else {
    s = (int)ei[e];
    d = (int)ei[(size_t)NEDGES + e];
  }
  src32[e] = clampn(s);
  dst32[e] = clampn(d);
}

// ---- atomic-free windowed histogram (R14-proven geometry) ----
__global__ __launch_bounds__(1024) void histw2_k(const int* __restrict__ dst32,
                                                 int* __restrict__ degp) {
  __shared__ int h[WIN];
  int b = blockIdx.x;
  int w = b >> 6, s = b & 63;
  for (int j = threadIdx.x; j < WIN; j += 1024) h[j] = 0;
  __syncthreads();
  int base = w * WIN;
  int e0 = s * SLICE, e1 = e0 + SLICE;
  for (int e = e0 + threadIdx.x; e < e1; e += 1024) {
    int j = dst32[e] - base;
    if ((unsigned)j < (unsigned)WIN) atomicAdd(&h[j], 1);
  }
  __syncthreads();
  int* dp = degp + (size_t)s * NNODES + base;
  for (int j = threadIdx.x; j < WIN; j += 1024) dp[j] = h[j];
}

__global__ void hreduce_k(int* __restrict__ degp, int* __restrict__ deg) {
  int n = blockIdx.x * blockDim.x + threadIdx.x;
  if (n >= NNODES) return;
  int run = 0;
  for (int s = 0; s < NSL; ++s) {
    size_t idx = (size_t)s * NNODES + n;
    int t = degp[idx];
    degp[idx] = run;
    run += t;
  }
  deg[n] = run;
}

// ---- hierarchical scan (proven) ----
__global__ __launch_bounds__(1024) void scan1_k(const int* __restrict__ deg, int* __restrict__ bsum) {
  __shared__ int wsum[16];
  int tid = threadIdx.x;
  int i = blockIdx.x * 1024 + tid;
  int v = (i < NNODES) ? deg[i] : 0;
  #pragma unroll
  for (int d = 32; d >= 1; d >>= 1) v += __shfl_down(v, d);
  if ((tid & 63) == 0) wsum[tid >> 6] = v;
  __syncthreads();
  if (tid == 0) {
    int t = 0;
    #pragma unroll
    for (int w = 0; w < 16; ++w) t += wsum[w];
    bsum[blockIdx.x] = t;
  }
}

__global__ void scan2_k(int* __restrict__ bsum, int* __restrict__ offs) {
  if (blockIdx.x == 0 && threadIdx.x == 0) {
    int run = 0;
    for (int b = 0; b < NB; ++b) { int t = bsum[b]; bsum[b] = run; run += t; }
    offs[NNODES] = run;
  }
}

__global__ __launch_bounds__(1024) void scan3_k(const int* __restrict__ deg, const int* __restrict__ bsum,
                                                int* __restrict__ offs, int* __restrict__ cursor,
                                                float* __restrict__ invd) {
  __shared__ int wsum[16];
  int tid = threadIdx.x;
  int lane = tid & 63, wid = tid >> 6;
  int i = blockIdx.x * 1024 + tid;
  int v = (i < NNODES) ? deg[i] : 0;
  int s = v;
  #pragma unroll
  for (int d = 1; d < 64; d <<= 1) {
    int t = __shfl_up(s, d);
    if (lane >= d) s += t;
  }
  if (lane == 63) wsum[wid] = s;
  __syncthreads();
  int wprefix = 0;
  #pragma unroll
  for (int w = 0; w < 16; ++w)
    if (w < wid) wprefix += wsum[w];
  if (i < NNODES) {
    int excl = bsum[blockIdx.x] + wprefix + s - v;
    offs[i] = excl;
    cursor[i] = excl;
    invd[i] = 1.0f / fmaxf((float)v, 1.0f);
  }
}

// ---- 4-pass windowed scatter (proven) ----
__global__ void scatter4_k(const int* __restrict__ src32, const int* __restrict__ dst32,
                           int* __restrict__ cursor, int* __restrict__ csr,
                           int lo, int hi) {
  int e = blockIdx.x * blockDim.x + threadIdx.x;
  if (e >= NEDGES) return;
  int d = dst32[e];
  if (d < lo || d >= hi) return;
  int p = atomicAdd(&cursor[d], 1);
  if (p >= 0 && p < NEDGES) csr[p] = src32[e];
}

// ---- cvt kernels (proven) ----
template <bool BF16>
__global__ void cvt_packx_k(const void* __restrict__ src, uint32_t* __restrict__ dst, int npairs,
                            const int* __restrict__ flags) {
  if (flags[0] != (BF16 ? 1 : 0)) return;
  int i = blockIdx.x * blockDim.x + threadIdx.x;
  if (i < npairs) {
    if constexpr (BF16) dst[i] = ((const uint32_t*)src)[i];
    else {
      const float* s = (const float*)src;
      dst[i] = pack2(s[2 * i], s[2 * i + 1]);
    }
  }
}

template <bool BF16>
__global__ void cvt_outp_k(const uint32_t* __restrict__ src, void* __restrict__ dst, int npairs,
                           const int* __restrict__ flags) {
  if (flags[0] != (BF16 ? 1 : 0)) return;
  int i = blockIdx.x * blockDim.x + threadIdx.x;
  if (i < npairs) {
    if constexpr (BF16) ((uint32_t*)dst)[i] = src[i];
    else {
      uint32_t w = src[i];
      float* d = (float*)dst;
      d[2 * i] = blo(w);
      d[2 * i + 1] = bhi(w);
    }
  }
}

template <bool BF16>
__global__ void cvt_out_k(const float* __restrict__ src, void* __restrict__ dst, int n,
                          const int* __restrict__ flags) {
  if (flags[0] != (BF16 ? 1 : 0)) return;
  int i = blockIdx.x * blockDim.x + threadIdx.x;
  if (i < n) {
    if constexpr (BF16) ((ushort_t*)dst)[i] = f2b(src[i]);
    else ((float*)dst)[i] = src[i];
  }
}

struct WPtrs { const void* p[18]; int sz[18]; int off[18]; };

template <bool BF16>
__global__ void cvt_w_k(WPtrs w, float* __restrict__ dst, const int* __restrict__ flags) {
  if (flags[0] != (BF16 ? 1 : 0)) return;
  int a = blockIdx.x;
  int sz = w.sz[a], off = w.off[a];
  for (int t = threadIdx.x; t < sz; t += blockDim.x) {
    dst[off + t] = BF16 ? b2f(((const ushort_t*)w.p[a])[t]) : ((const float*)w.p[a])[t];
  }
}

// ---- F=3 aggregation (proven) ----
template <bool ADD_U>
__global__ __launch_bounds__(256) void agg3_k(const float* __restrict__ feat, const int* __restrict__ csr,
                                              const int* __restrict__ offs, const float* __restrict__ invd,
                                              const float* __restrict__ u, float* __restrict__ out) {
  int n = blockIdx.x * blockDim.x + threadIdx.x;
  if (n >= NNODES) return;
  int k0 = offs[n], k1 = offs[n + 1];
  float a0 = 0.f, a1 = 0.f, a2 = 0.f;
  int k = k0;
  for (; k + 4 <= k1; k += 4) {
    const float* r0 = feat + (size_t)clampn(csr[k]) * 3;
    const float* r1 = feat + (size_t)clampn(csr[k + 1]) * 3;
    const float* r2 = feat + (size_t)clampn(csr[k + 2]) * 3;
    const float* r3 = feat + (size_t)clampn(csr[k + 3]) * 3;
    a0 += r0[0] + r1[0] + r2[0] + r3[0];
    a1 += r0[1] + r1[1] + r2[1] + r3[1];
    a2 += r0[2] + r1[2] + r2[2] + r3[2];
  }
  for (; k < k1; ++k) {
    const float* r = feat + (size_t)clampn(csr[k]) * 3;
    a0 += r[0]; a1 += r[1]; a2 += r[2];
  }
  float iv = invd[n];
  a0 *= iv; a1 *= iv; a2 *= iv;
  if constexpr (ADD_U) {
    a0 += u[(size_t)n * 3];
    a1 += u[(size_t)n * 3 + 1];
    a2 += u[(size_t)n * 3 + 2];
  }
  out[(size_t)n * 3]     = a0;
  out[(size_t)n * 3 + 1] = a1;
  out[(size_t)n * 3 + 2] = a2;
}

// ---- packed-bf16 aggregation v5: 16-deep gather pipeline (R17 v4 + deeper unroll) ----
template <int PAIRS, bool ADD_U>
__global__ __launch_bounds__(256) void aggp4_k(const uint32_t* __restrict__ feat, const int* __restrict__ csr,
                                               const int* __restrict__ offs, const float* __restrict__ invd,
                                               const uint32_t* __restrict__ u, uint32_t* __restrict__ out) {
  constexpr int HP = PAIRS / 2;
  int lane = threadIdx.x & 63;
  int n = (blockIdx.x * blockDim.x + threadIdx.x) >> 6;
  if (n >= NNODES) return;
  int q = lane >> 4;
  int p = lane & 15;
  int k0 = offs[n], k1 = offs[n + 1];
  float a0 = 0.f, a1 = 0.f, a2 = 0.f, a3 = 0.f;
  int k = k0;
  for (; k + 16 <= k1; k += 16) {
    int r0 = clampn(csr[k + q]);
    int r1 = clampn(csr[k + 4 + q]);
    int r2 = clampn(csr[k + 8 + q]);
    int r3 = clampn(csr[k + 12 + q]);
    if (p < HP) {
      uint2 w0 = ((const uint2*)(feat + (size_t)r0 * PAIRS))[p];
      uint2 w1 = ((const uint2*)(feat + (size_t)r1 * PAIRS))[p];
      uint2 w2 = ((const uint2*)(feat + (size_t)r2 * PAIRS))[p];
      uint2 w3 = ((const uint2*)(feat + (size_t)r3 * PAIRS))[p];
      a0 += blo(w0.x) + blo(w1.x) + blo(w2.x) + blo(w3.x);
      a1 += bhi(w0.x) + bhi(w1.x) + bhi(w2.x) + bhi(w3.x);
      a2 += blo(w0.y) + blo(w1.y) + blo(w2.y) + blo(w3.y);
      a3 += bhi(w0.y) + bhi(w1.y) + bhi(w2.y) + bhi(w3.y);
    }
  }
  for (; k + 8 <= k1; k += 8) {
    int r0 = clampn(csr[k + q]);
    int r1 = clampn(csr[k + 4 + q]);
    if (p < HP) {
      uint2 w0 = ((const uint2*)(feat + (size_t)r0 * PAIRS))[p];
      uint2 w1 = ((const uint2*)(feat + (size_t)r1 * PAIRS))[p];
      a0 += blo(w0.x) + blo(w1.x);
      a1 += bhi(w0.x) + bhi(w1.x);
      a2 += blo(w0.y) + blo(w1.y);
      a3 += bhi(w0.y) + bhi(w1.y);
    }
  }
  for (; k + 4 <= k1; k += 4) {
    int r0 = clampn(csr[k + q]);
    if (p < HP) {
      uint2 w0 = ((const uint2*)(feat + (size_t)r0 * PAIRS))[p];
      a0 += blo(w0.x); a1 += bhi(w0.x); a2 += blo(w0.y); a3 += bhi(w0.y);
    }
  }
  int rem = k1 - k;
  if (q < rem && p < HP) {
    int r0 = clampn(csr[k + q]);
    uint2 w0 = ((const uint2*)(feat + (size_t)r0 * PAIRS))[p];
    a0 += blo(w0.x); a1 += bhi(w0.x); a2 += blo(w0.y); a3 += bhi(w0.y);
  }
  a0 += __shfl_xor(a0, 16); a0 += __shfl_xor(a0, 32);
  a1 += __shfl_xor(a1, 16); a1 += __shfl_xor(a1, 32);
  a2 += __shfl_xor(a2, 16); a2 += __shfl_xor(a2, 32);
  a3 += __shfl_xor(a3, 16); a3 += __shfl_xor(a3, 32);
  if (q == 0 && p < HP) {
    float iv = invd[n];
    float v0 = a0 * iv, v1 = a1 * iv, v2 = a2 * iv, v3 = a3 * iv;
    if constexpr (ADD_U) {
      uint2 uw = ((const uint2*)(u + (size_t)n * PAIRS))[p];
      v0 += blo(uw.x); v1 += bhi(uw.x); v2 += blo(uw.y); v3 += bhi(uw.y);
    }
    uint2 ow;
    ow.x = pack2(v0, v1);
    ow.y = pack2(v2, v3);
    ((uint2*)(out + (size_t)n * PAIRS))[p] = ow;
  }
}

// ---- MFMA fused linear (byte-identical to R17) ----
template <int F_IN, int F_OUT, bool DUAL, bool RELU, bool PIN, bool POUT>
__global__ __launch_bounds__(256) void mgemm_k(const void* __restrict__ Av, const void* __restrict__ Bv,
                                               const float* __restrict__ W1, const float* __restrict__ W2,
                                               const float* __restrict__ Wb,
                                               void* __restrict__ C1v, void* __restrict__ C2v) {
  constexpr int KS = (F_IN + 31) / 32;
  constexpr int JT = (F_OUT + 15) / 16;
  constexpr int PP = F_IN / 2;
  int lane = threadIdx.x & 63;
  int wid  = threadIdx.x >> 6;
  int tile = blockIdx.x * 4 + wid;
  if (tile * 16 >= NNODES) return;
  int l15 = lane & 15, l4 = lane >> 4;

  bf16x8 w1f[KS][JT], w2f[KS][JT];
  float bv[JT];
  #pragma unroll
  for (int ks = 0; ks < KS; ++ks) {
    #pragma unroll
    for (int jt = 0; jt < JT; ++jt) {
      int col = jt * 16 + l15;
      #pragma unroll
      for (int j = 0; j < 8; ++j) {
        int k = ks * 32 + l4 * 8 + j;
        bool ok = (k < F_IN) && (col < F_OUT);
        w1f[ks][jt][j] = ok ? (short)f2b(W1[k * F_OUT + col]) : (short)0;
        w2f[ks][jt][j] = ok ? (short)f2b(W2[k * F_OUT + col]) : (short)0;
      }
    }
  }
  #pragma unroll
  for (int jt = 0; jt < JT; ++jt) {
    int col = jt * 16 + l15;
    bv[jt] = (col < F_OUT) ? Wb[col] : 0.f;
  }

  int row = tile * 16 + l15;
  bf16x8 af[KS], bfr[KS];
  if constexpr (PIN) {
    const uint32_t* Arow = (const uint32_t*)Av + (size_t)row * PP;
    #pragma unroll
    for (int ks = 0; ks < KS; ++ks) {
      #pragma unroll
      for (int w4 = 0; w4 < 4; ++w4) {
        int word = ks * 16 + l4 * 4 + w4;
        uint32_t v = (word < PP) ? Arow[word] : 0u;
        af[ks][2 * w4]     = (short)(v & 0xffffu);
        af[ks][2 * w4 + 1] = (short)(v >> 16);
      }
    }
    if constexpr (!DUAL) {
      const uint32_t* Brow = (const uint32_t*)Bv + (size_t)row * PP;
      #pragma unroll
      for (int ks = 0; ks < KS; ++ks) {
        #pragma unroll
        for (int w4 = 0; w4 < 4; ++w4) {
          int word = ks * 16 + l4 * 4 + w4;
          uint32_t v = (word < PP) ? Brow[word] : 0u;
          bfr[ks][2 * w4]     = (short)(v & 0xffffu);
          bfr[ks][2 * w4 + 1] = (short)(v >> 16);
        }
      }
    }
  } else {
    const float* Arow = (const float*)Av + (size_t)row * F_IN;
    #pragma unroll
    for (int ks = 0; ks < KS; ++ks) {
      #pragma unroll
      for (int j = 0; j < 8; ++j) {
        int k = ks * 32 + l4 * 8 + j;
        af[ks][j] = (k < F_IN) ? (short)f2b(Arow[k]) : (short)0;
      }
    }
    if constexpr (!DUAL) {
      const float* Brow = (const float*)Bv + (size_t)row * F_IN;
      #pragma unroll
      for (int ks = 0; ks < KS; ++ks) {
        #pragma unroll
        for (int j = 0; j < 8; ++j) {
          int k = ks * 32 + l4 * 8 + j;
          bfr[ks][j] = (k < F_IN) ? (short)f2b(Brow[k]) : (short)0;
        }
      }
    }
  }

  f32x4 acc1[JT], acc2[DUAL ? JT : 1];
  #pragma unroll
  for (int jt = 0; jt < JT; ++jt) {
    acc1[jt] = (f32x4)(0.f);
    if constexpr (DUAL) acc2[jt] = (f32x4)(0.f);
  }

  #pragma unroll
  for (int ks = 0; ks < KS; ++ks) {
    #pragma unroll
    for (int jt = 0; jt < JT; ++jt) {
      acc1[jt] = __builtin_amdgcn_mfma_f32_16x16x32_bf16(af[ks], w1f[ks][jt], acc1[jt], 0, 0, 0);
      if constexpr (DUAL)
        acc2[jt] = __builtin_amdgcn_mfma_f32_16x16x32_bf16(af[ks], w2f[ks][jt], acc2[jt], 0, 0, 0);
      else
        acc1[jt] = __builtin_amdgcn_mfma_f32_16x16x32_bf16(bfr[ks], w2f[ks][jt], acc1[jt], 0, 0, 0);
    }
  }

  #pragma unroll
  for (int jt = 0; jt < JT; ++jt) {
    int col = jt * 16 + l15;
    #pragma unroll
    for (int r = 0; r < 4; ++r) {
      int orow = tile * 16 + l4 * 4 + r;
      if constexpr (DUAL) {
        float v1 = acc1[jt][r];
        float v2 = acc2[jt][r] + bv[jt];
        if constexpr (POUT) {
          float p1 = __shfl_xor(v1, 1);
          float p2 = __shfl_xor(v2, 1);
          if (((lane & 1) == 0) && col < F_OUT) {
            ((uint32_t*)C1v)[(size_t)orow * (F_OUT / 2) + (col >> 1)] = pack2(v1, p1);
            ((uint32_t*)C2v)[(size_t)orow * (F_OUT / 2) + (col >> 1)] = pack2(v2, p2);
          }
        } else {
          if (col < F_OUT) {
            ((float*)C1v)[(size_t)orow * F_OUT + col] = v1;
            ((float*)C2v)[(size_t)orow * F_OUT + col] = v2;
          }
        }
      } else {
        float v = acc1[jt][r] + bv[jt];
        if constexpr (RELU) v = fmaxf(v, 0.f);
        if constexpr (POUT) {
          float pv = __shfl_xor(v, 1);
          if (((lane & 1) == 0) && col < F_OUT)
            ((uint32_t*)C1v)[(size_t)orow * (F_OUT / 2) + (col >> 1)] = pack2(v, pv);
        } else {
          if (col < F_OUT)
            ((float*)C1v)[(size_t)orow * F_OUT + col] = v;
        }
      }
    }
  }
}

extern "C" void kernel_launch(void* const* d_in, const int* in_sizes, int n_in,
                              void* d_out, int out_size, void* d_ws, size_t ws_size,
                              hipStream_t stream) {
  const uint32_t* xw = (const uint32_t*)d_in[0];
  const uint32_t* ei = (const uint32_t*)d_in[1];

  char* ws = (char*)d_ws;
  size_t off = 0;
  auto carve = [&](size_t bytes) -> char* {
    char* p = ws + off;
    off = (off + bytes + 255) & ~(size_t)255;
    return p;
  };
  int* flags     = (int*)carve(8);
  int* deg       = (int*)carve((size_t)NNODES * 4);
  int* offs      = (int*)carve((size_t)(NNODES + 1) * 4);
  int* cursor    = (int*)carve((size_t)NNODES * 4);
  float* invd    = (float*)carve((size_t)NNODES * 4);
  int* bsum      = (int*)carve((size_t)NB * 4);
  int* csr       = (int*)carve((size_t)NEDGES * 4);
  float* wf      = (float*)carve((size_t)32768 * 4);
  uint32_t* xp   = (uint32_t*)carve((size_t)NNODES * 20 * 4);
  uint32_t* mp   = (uint32_t*)carve((size_t)NNODES * 20 * 4);
  uint32_t* b0p  = (uint32_t*)carve((size_t)NNODES * 32 * 4);
  uint32_t* b1p  = (uint32_t*)carve((size_t)NNODES * 32 * 4);
  uint32_t* b2p  = (uint32_t*)carve((size_t)NNODES * 32 * 4);
  uint32_t* y40p = (uint32_t*)carve((size_t)NNODES * 20 * 4);
  uint32_t* u40p = (uint32_t*)carve((size_t)NNODES * 20 * 4);
  uint32_t* xrp  = (uint32_t*)carve((size_t)NNODES * 20 * 4);
  float* y3f     = (float*)carve((size_t)NNODES * 3 * 4);
  float* u3f     = (float*)carve((size_t)NNODES * 3 * 4);
  float* zf      = (float*)carve((size_t)NNODES * 3 * 4);
  float* m3f     = (float*)carve((size_t)NNODES * 3 * 4);

  // degp overlays b0p+b1p (25.6 MB); src32/dst32 overlays b2p (12.8 MB). All first
  // written by enc1/enc2 kernels, strictly after the CSR build completes.
  int* degp = (int*)b0p;
  int* src32 = (int*)b2p;
  int* dst32 = src32 + NEDGES;

  static const int wsz[18] = {2560, 2560, 64, 4096, 4096, 64, 192, 192, 3,
                              192, 192, 64, 4096, 4096, 64, 2560, 2560, 40};
  WPtrs wp;
  int woff = 0;
  for (int i = 0; i < 18; ++i) {
    wp.p[i] = d_in[2 + i];
    wp.sz[i] = wsz[i];
    wp.off[i] = woff;
    woff += wsz[i];
  }
  const float* W[18];
  for (int i = 0; i < 18; ++i) W[i] = wf + wp.off[i];

  // ---- detect + CSR build (R17-proven; csr zero-fill dropped: scatter4 covers all slots) ----
  detect_k<<<1, 64, 0, stream>>>(xw, ei, flags);
  const int EB = (NEDGES + 255) / 256;
  cvt_e32_k<<<EB, 256, 0, stream>>>(ei, src32, dst32, flags);
  histw2_k<<<4 * NSL, 1024, 0, stream>>>(dst32, degp);
  hreduce_k<<<(NNODES + 255) / 256, 256, 0, stream>>>(degp, deg);
  scan1_k<<<NB, 1024, 0, stream>>>(deg, bsum);
  scan2_k<<<1, 64, 0, stream>>>(bsum, offs);
  scan3_k<<<NB, 1024, 0, stream>>>(deg, bsum, offs, cursor, invd);
  scatter4_k<<<EB, 256, 0, stream>>>(src32, dst32, cursor, csr, 0, 25000);
  scatter4_k<<<EB, 256, 0, stream>>>(src32, dst32, cursor, csr, 25000, 50000);
  scatter4_k<<<EB, 256, 0, stream>>>(src32, dst32, cursor, csr, 50000, 75000);
  scatter4_k<<<EB, 256, 0, stream>>>(src32, dst32, cursor, csr, 75000, 100000);

  // ---- convert x (packed) + weights (f32 arena) ----
  const int NXP = NNODES * 20;
  cvt_packx_k<false><<<(NXP + 255) / 256, 256, 0, stream>>>(d_in[0], xp, NXP, flags);
  cvt_packx_k<true ><<<(NXP + 255) / 256, 256, 0, stream>>>(d_in[0], xp, NXP, flags);
  cvt_w_k<false><<<18, 256, 0, stream>>>(wp, wf, flags);
  cvt_w_k<true ><<<18, 256, 0, stream>>>(wp, wf, flags);

  const int AGGW_BLOCKS = (NNODES * 64 + 255) / 256;
  const int AGG3_BLOCKS = (NNODES + 255) / 256;
  const int MG = (NNODES / 16 + 3) / 4;

  // enc1 (40 -> 64)
  aggp4_k<20, false><<<AGGW_BLOCKS, 256, 0, stream>>>(xp, csr, offs, invd, nullptr, mp);
  mgemm_k<40, 64, false, true, true, true><<<MG, 256, 0, stream>>>(mp, xp, W[0], W[1], W[2], b1p, nullptr);
  // enc2 (64 -> 64)
  aggp4_k<32, false><<<AGGW_BLOCKS, 256, 0, stream>>>(b1p, csr, offs, invd, nullptr, b0p);
  mgemm_k<64, 64, false, true, true, true><<<MG, 256, 0, stream>>>(b0p, b1p, W[3], W[4], W[5], b2p, nullptr);
  // enc3 (64 -> 3): transform-first; z path f32
  mgemm_k<64, 3, true, false, true, false><<<MG, 256, 0, stream>>>(b2p, nullptr, W[6], W[7], W[8], y3f, u3f);
  agg3_k<true><<<AGG3_BLOCKS, 256, 0, stream>>>(y3f, csr, offs, invd, u3f, zf);
  // dec1 (3 -> 64)
  agg3_k<false><<<AGG3_BLOCKS, 256, 0, stream>>>(zf, csr, offs, invd, nullptr, m3f);
  mgemm_k<3, 64, false, true, false, true><<<MG, 256, 0, stream>>>(m3f, zf, W[9], W[10], W[11], b1p, nullptr);
  // dec2 (64 -> 64)
  aggp4_k<32, false><<<AGGW_BLOCKS, 256, 0, stream>>>(b1p, csr, offs, invd, nullptr, b0p);
  mgemm_k<64, 64, false, true, true, true><<<MG, 256, 0, stream>>>(b0p, b1p, W[12], W[13], W[14], b2p, nullptr);
  // dec3 (64 -> 40): transform-first
  mgemm_k<64, 40, true, false, true, true><<<MG, 256, 0, stream>>>(b2p, nullptr, W[15], W[16], W[17], y40p, u40p);
  aggp4_k<20, true><<<AGGW_BLOCKS, 256, 0, stream>>>(y40p, csr, offs, invd, u40p, xrp);

  // ---- outputs (proven) ----
  const int NX = NNODES * 40;
  const int NZ = NNODES * 3;
  cvt_outp_k<false><<<(NXP + 255) / 256, 256, 0, stream>>>(xrp, d_out, NXP, flags);
  cvt_outp_k<true ><<<(NXP + 255) / 256, 256, 0, stream>>>(xrp, d_out, NXP, flags);
  cvt_out_k<false><<<(NZ + 255) / 256, 256, 0, stream>>>(zf, (float*)d_out + NX, NZ, flags);
  cvt_out_k<true ><<<(NZ + 255) / 256, 256, 0, stream>>>(zf, (ushort_t*)d_out + NX, NZ, flags);
  (void)in_sizes; (void)n_in; (void)out_size; (void)ws_size;
}